// Round 3
// baseline (3294064.062 us; speedup 1.0000x reference)
//
#include <hip/hip_runtime.h>

typedef _Float16 h16x8 __attribute__((ext_vector_type(8)));
typedef _Float16 h16x4 __attribute__((ext_vector_type(4)));
typedef float fx4 __attribute__((ext_vector_type(4)));
typedef unsigned int u32x4 __attribute__((ext_vector_type(4)));
typedef unsigned long long ull;

// V=32001 E=512 H=512 LE=512 B=128 T=512, 5H=2560
#define PRE_S 2560.0f
#define PRE_INV (1.0f / 2560.0f)

// ---------------- fp32 -> fp16 bulk convert (i2h weights) ----------------
__global__ __launch_bounds__(256) void f2h_kernel(const float* __restrict__ src,
                                                  _Float16* __restrict__ dst,
                                                  int n4) {
  int i = blockIdx.x * 256 + threadIdx.x;
  if (i < n4) {
    float4 v = ((const float4*)src)[i];
    h16x4 o = {(_Float16)v.x, (_Float16)v.y, (_Float16)v.z, (_Float16)v.w};
    *(h16x4*)&dst[i * 4] = o;
  }
}

// ---------------- pre = gather(embed) @ i2h_w^T, int8 out (x2560 scale)
// pre8 layout (round-0, coalesced writes): pre8[t][j=64][b=128][g=5][u=8]
__global__ __launch_bounds__(256) void gemm1_kernel(
    const int* __restrict__ label, const int* __restrict__ label_len,
    const float* __restrict__ embed_w,        // fp32 [32001][512]
    const _Float16* __restrict__ Bh,          // i2h fp16 [2560][512]
    signed char* __restrict__ pre8) {
  const int bx = blockIdx.x;          // N tile 0..19
  const int by = blockIdx.y;          // M tile 0..511
  const int bidx = by >> 2;           // batch
  const int t0 = (by & 3) * 128;      // t range start
  if (t0 > label_len[bidx]) return;   // this tile's pre is never read

  const int tid = threadIdx.x;
  const int lane = tid & 63;
  const int wv = tid >> 6;
  const int wm = (wv & 1) * 64;
  const int wn = (wv >> 1) * 64;

  __shared__ _Float16 As[128 * 40];
  __shared__ _Float16 Bs[128 * 40];

  fx4 zero = {0.f, 0.f, 0.f, 0.f};
  fx4 acc[4][4];
  for (int a = 0; a < 4; a++)
    for (int b = 0; b < 4; b++) acc[a][b] = zero;

#pragma unroll 1
  for (int k0 = 0; k0 < 512; k0 += 32) {
#pragma unroll
    for (int q = 0; q < 2; q++) {
      int chunk = tid + q * 256;
      int row = chunk >> 2;
      int ko = (chunk & 3) * 8;
      int arow = label[bidx * 512 + t0 + row];
      const float* ap = &embed_w[(size_t)arow * 512 + k0 + ko];
      float4 a0 = *(const float4*)ap;
      float4 a1 = *(const float4*)(ap + 4);
      h16x8 av = {(_Float16)a0.x, (_Float16)a0.y, (_Float16)a0.z, (_Float16)a0.w,
                  (_Float16)a1.x, (_Float16)a1.y, (_Float16)a1.z, (_Float16)a1.w};
      h16x8 bv = *(const h16x8*)&Bh[(size_t)(bx * 128 + row) * 512 + k0 + ko];
      *(h16x8*)&As[row * 40 + ko] = av;
      *(h16x8*)&Bs[row * 40 + ko] = bv;
    }
    __syncthreads();
    h16x8 af[4], bfr[4];
#pragma unroll
    for (int i = 0; i < 4; i++) {
      af[i]  = *(const h16x8*)&As[(wm + i * 16 + (lane & 15)) * 40 + (lane >> 4) * 8];
      bfr[i] = *(const h16x8*)&Bs[(wn + i * 16 + (lane & 15)) * 40 + (lane >> 4) * 8];
    }
#pragma unroll
    for (int mi = 0; mi < 4; mi++)
#pragma unroll
      for (int ni = 0; ni < 4; ni++)
        acc[mi][ni] = __builtin_amdgcn_mfma_f32_16x16x32_f16(af[mi], bfr[ni], acc[mi][ni], 0, 0, 0);
    __syncthreads();
  }

#pragma unroll
  for (int mi = 0; mi < 4; mi++)
#pragma unroll
    for (int ni = 0; ni < 4; ni++)
#pragma unroll
      for (int r = 0; r < 4; r++) {
        int rowm = wm + mi * 16 + (lane >> 4) * 4 + r;
        int t = t0 + rowm;
        int n = bx * 128 + wn + ni * 16 + (lane & 15);
        float v = acc[mi][ni][r] * PRE_S;
        int q = (int)rintf(v);
        q = q > 127 ? 127 : (q < -127 ? -127 : q);
        int g = n >> 9, ju = n & 511, j = ju >> 3, uu = ju & 7;
        pre8[(((size_t)t * 64 + j) * 128 + bidx) * 40 + g * 8 + uu] = (signed char)q;
      }
}

// ---------------- persistent LSTM scan: XCD-pinned L2 synchronization.
// 1024 WGs launched; each reads its XCC_ID. First 32 WGs on XCD0 run recurrence
// bh=0, first 32 on XCD1 run bh=1, rest exit. All h/flag exchange via plain
// stores + sc0 loads -> served by the shared per-XCD L2 (~200cy hops instead of
// LLC/HBM ~600-1000cy). Elected WG (jj,bh) owns units [16jj,16jj+16) x batches
// [64bh,64bh+64). Gates fully in-register from the MFMA C-fragment (gate g =
// n-tile nt, unit = lane&15, batch = wv*16+(lane>>4)*4+r).
// ALL spin loops are bounded: a protocol failure degrades to a finishing run
// (wrong numerics at worst) instead of a GPU hang with zero diagnostics.
// flags int layout (16KB memset region): [0..2047]  per-producer flags (128B apart)
//   [2048+xcd*32]        election tickets (LLC scope)
//   [2560+bh*32]         startup arrive counters (LLC scope)
#define NPROD 32
__global__ __launch_bounds__(256, 1) void lstm_kernel(
    const int* __restrict__ label_len,
    const float* __restrict__ h2h_w,   // [2560][512] fp32
    const float* __restrict__ h2h_b,   // [2560]
    const float* __restrict__ i2h_b,   // [2560]
    const signed char* __restrict__ pre8,    // [512][64][128][5][8] int8
    _Float16* __restrict__ hfrag,            // [2][8*16][64][8] fp16 (256 KB)
    float* __restrict__ xsel,                // [128][512] fp32
    int* __restrict__ flags) {
  const int tid = threadIdx.x;
  const int lane = tid & 63;
  const int wv = tid >> 6;

  __shared__ _Float16 Wl[5 * 16 * 64 * 8];   // 80 KB, MFMA B-operand order
  __shared__ _Float16 hstage[64 * 16];       // 2 KB repack stage
  __shared__ int ll_s[64];
  __shared__ int role_s;

  // ---- election: pin each recurrence to one XCD ----
  if (tid == 0) {
    int xcd;
    asm volatile("s_getreg_b32 %0, hwreg(HW_REG_XCC_ID)" : "=s"(xcd));
    xcd &= 7;
    int role = -1;
    if (xcd < 2) {
      int tk = __hip_atomic_fetch_add(&flags[2048 + xcd * 32], 1,
                                      __ATOMIC_RELAXED, __HIP_MEMORY_SCOPE_AGENT);
      if (tk < NPROD) role = (xcd << 5) | tk;
    }
    role_s = role;
  }
  __syncthreads();
  const int role = role_s;
  if (role < 0) return;
  const int bh = role >> 5;    // XCD index == batch half
  const int jj = role & 31;    // unit tile

  int* const fown = flags + (bh * 32 + jj) * 32;

  // reset own L2 flag (plain store -> updates this XCD's L2 copy, fixing any
  // cross-replay staleness), then arrive on the LLC-scope startup barrier.
  if (tid == 0) {
    int zero = 0;
    asm volatile("global_store_dword %0, %1, off\n\ts_waitcnt vmcnt(0)"
                 :: "v"(fown), "v"(zero) : "memory");
    __hip_atomic_fetch_add(&flags[2560 + bh * 32], 1,
                           __ATOMIC_RELAXED, __HIP_MEMORY_SCOPE_AGENT);
  }

  // ---- stage h2h weights: n-tile nt = gate g, col-within-tile = unit u ----
  for (int slot = tid; slot < 5 * 16 * 64; slot += 256) {
    int nt = slot >> 10;             // /(16*64)
    int rem = slot & 1023;
    int kt = rem >> 6;
    int l = rem & 63;
    int r = nt * 512 + jj * 16 + (l & 15);
    int k0 = kt * 32 + (l >> 4) * 8;
    const float* src = h2h_w + (size_t)r * 512 + k0;
    h16x8 tv;
#pragma unroll
    for (int q = 0; q < 8; q++) tv[q] = (_Float16)src[q];
    *(h16x8*)&Wl[slot * 8] = tv;
  }
  if (tid < 64) ll_s[tid] = label_len[bh * 64 + tid];
  __syncthreads();

  // startup barrier (bounded): all 32 producers of this group reset their flags
  if (tid == 0) {
    for (int it = 0; it < (1 << 20); ++it) {
      if (__hip_atomic_load(&flags[2560 + bh * 32], __ATOMIC_RELAXED,
                            __HIP_MEMORY_SCOPE_AGENT) >= NPROD) break;
      __builtin_amdgcn_s_sleep(2);
    }
  }
  __syncthreads();

  int tmax = 0;
#pragma unroll 1
  for (int i = 0; i < 64; i++) tmax = max(tmax, ll_s[i]);
  tmax += 1;

  // gate ownership straight from the C-fragment: unit u, batches b4..b4+3
  const int u = lane & 15;
  const int b4 = wv * 16 + (lane >> 4) * 4;
  float bias_r[5];
#pragma unroll
  for (int g = 0; g < 5; g++)
    bias_r[g] = h2h_b[g * 512 + jj * 16 + u] + i2h_b[g * 512 + jj * 16 + u];

  // producer packed-store slot (fragment-major hfrag)
  const int bp = tid >> 2;             // local batch 0..63
  const int ue = (tid & 3) * 4;        // 4 units
  const int pbb = (bh * 4 + (bp >> 4)) * 16 + (jj >> 1);
  const int pl2 = (bp & 15) | ((2 * (jj & 1) + (ue >> 3)) << 4);
  ull* pdst0 = (ull*)(hfrag + (size_t)pbb * 512 + pl2 * 8 + (ue & 4));
  ull* pdst1 = (ull*)(hfrag + 65536 + (size_t)pbb * 512 + pl2 * 8 + (ue & 4));

  const int* pollp = flags + (bh * 32 + (lane & 31)) * 32;

  float c_reg[4] = {0.f, 0.f, 0.f, 0.f};

#pragma unroll 1
  for (int t = 0; t < tmax; ++t) {
    // prefetch this lane's pre8 bytes (5 gates x 4 batches); issued before the
    // poll so the HBM/LLC latency hides under the wait.
    signed char pv[5][4];
    {
      const signed char* pt = pre8
          + ((size_t)(t * 64 + jj * 2 + (u >> 3)) * 128 + bh * 64 + b4) * 40 + (u & 7);
#pragma unroll
      for (int g = 0; g < 5; g++)
#pragma unroll
        for (int r = 0; r < 4; r++)
          pv[g][r] = pt[r * 40 + g * 8];
    }

    fx4 acc[5] = {};
    if (t > 0) {
      // wait for all 32 same-group producers (lane-parallel flags, L2 sc0
      // loads). Bounded: ~65K polls (~3ms) worst case, never hit when healthy.
      if (wv == 0) {
        for (int it = 0; it < (1 << 16); ++it) {
          int v;
          asm volatile("global_load_dword %0, %1, off sc0\n\ts_waitcnt vmcnt(0)"
                       : "=v"(v) : "v"(pollp) : "memory");
          if (__ballot(v >= t) == 0xFFFFFFFFFFFFFFFFull) break;
          __builtin_amdgcn_s_sleep(1);
        }
      }
      __syncthreads();

      // 16 A-fragments: contiguous 1KB blocks from the XCD-local L2
      const _Float16* hpb = hfrag + ((t - 1) & 1) * 65536
                          + (size_t)((bh * 4 + wv) * 16) * 512 + lane * 8;
      u32x4 areg[16];
#pragma unroll
      for (int kt = 0; kt < 16; ++kt) {
        const void* ap = (const void*)(hpb + kt * 512);
        asm volatile("global_load_dwordx4 %0, %1, off sc0"
                     : "=v"(areg[kt]) : "v"(ap) : "memory");
      }

      // counted-vmcnt chunks: overlap L2 latency with MFMA issue
#define GCHUNK(K0, VCSTR)                                                        \
      asm volatile("s_waitcnt vmcnt(" VCSTR ")" ::: "memory");                   \
      __builtin_amdgcn_sched_barrier(0);                                         \
      _Pragma("unroll")                                                          \
      for (int kt = (K0); kt < (K0) + 4; ++kt) {                                 \
        union { u32x4 uu; h16x8 v; } aa;                                         \
        aa.uu = areg[kt];                                                        \
        _Pragma("unroll")                                                        \
        for (int nt = 0; nt < 5; nt++) {                                         \
          h16x8 bfr = *(const h16x8*)&Wl[((nt * 16 + kt) * 64 + lane) * 8];      \
          acc[nt] = __builtin_amdgcn_mfma_f32_16x16x32_f16(aa.v, bfr, acc[nt], 0, 0, 0); \
        }                                                                        \
      }
      GCHUNK(0, "12")
      GCHUNK(4, "8")
      GCHUNK(8, "4")
      GCHUNK(12, "0")
#undef GCHUNK
    }

    // gates fully in-register (fp32 GEMM result, no LDS round trip)
#pragma unroll
    for (int r = 0; r < 4; r++) {
      float sv[5];
#pragma unroll
      for (int g = 0; g < 5; g++)
        sv[g] = acc[g][r] + (float)pv[g][r] * PRE_INV + bias_r[g];
      float ing = __builtin_amdgcn_rcpf(1.f + __expf(-sv[0]));
      float fg  = __builtin_amdgcn_rcpf(1.f + __expf(-sv[1]));
      float og  = __builtin_amdgcn_rcpf(1.f + __expf(-sv[2]));
      float itv = fmaxf(sv[3], sv[4]);
      float nc  = fg * c_reg[r] + ing * itv;
      c_reg[r] = nc;
      float nh = og * (1.f - 2.f * __builtin_amdgcn_rcpf(__expf(2.f * nc) + 1.f));
      hstage[(b4 + r) * 16 + u] = (_Float16)nh;
      if (ll_s[b4 + r] == t)
        __hip_atomic_store(&xsel[(bh * 64 + b4 + r) * 512 + jj * 16 + u], nh,
                           __ATOMIC_RELAXED, __HIP_MEMORY_SCOPE_AGENT);
    }
    __syncthreads();

    // packed 8B h store (4 units), plain store -> this XCD's L2
    {
      union { h16x4 h4; ull u8; } pk;
      pk.h4 = *(const h16x4*)&hstage[bp * 16 + ue];
      ull* dst = (t & 1) ? pdst1 : pdst0;
      asm volatile("global_store_dwordx2 %0, %1, off"
                   :: "v"(dst), "v"(pk.u8) : "memory");
    }

    // drain h stores to L2, then arrive on our own flag line (plain store)
    asm volatile("s_waitcnt vmcnt(0)" ::: "memory");
    __syncthreads();
    if (tid == 0) {
      int tv = t + 1;
      asm volatile("global_store_dword %0, %1, off"
                   :: "v"(fown), "v"(tv) : "memory");
    }
  }
}

// ---------------- small fp32 GEMM: Y[128,512] = X[128,512] @ W[512,512]^T + bias
__global__ __launch_bounds__(256) void fgemm_kernel(
    const float* __restrict__ X, const float* __restrict__ W,
    const float* __restrict__ bias, float* __restrict__ Y) {
  const int n0 = blockIdx.x * 64;
  const int m0 = blockIdx.y * 64;
  const int tid = threadIdx.x;
  const int tx = tid & 15, ty = tid >> 4;

  __shared__ float Xs[64 * 68];
  __shared__ float Wt[64 * 68];

  float acc[4][4] = {};
#pragma unroll 1
  for (int k0 = 0; k0 < 512; k0 += 64) {
#pragma unroll
    for (int q = 0; q < 4; q++) {
      int id = tid + q * 256;
      int r = id >> 4, c = id & 15;
      float4 xv = *(const float4*)&X[(m0 + r) * 512 + k0 + c * 4];
      *(float4*)&Xs[r * 68 + c * 4] = xv;
      float4 wvv = *(const float4*)&W[(n0 + r) * 512 + k0 + c * 4];
      Wt[(c * 4 + 0) * 68 + r] = wvv.x;
      Wt[(c * 4 + 1) * 68 + r] = wvv.y;
      Wt[(c * 4 + 2) * 68 + r] = wvv.z;
      Wt[(c * 4 + 3) * 68 + r] = wvv.w;
    }
    __syncthreads();
#pragma unroll 4
    for (int kk = 0; kk < 64; kk++) {
      float a[4], b[4];
#pragma unroll
      for (int i = 0; i < 4; i++) a[i] = Xs[(ty * 4 + i) * 68 + kk];
#pragma unroll
      for (int jj = 0; jj < 4; jj++) b[jj] = Wt[kk * 68 + tx * 4 + jj];
#pragma unroll
      for (int i = 0; i < 4; i++)
#pragma unroll
        for (int jj = 0; jj < 4; jj++) acc[i][jj] += a[i] * b[jj];
    }
    __syncthreads();
  }
#pragma unroll
  for (int i = 0; i < 4; i++)
#pragma unroll
    for (int jj = 0; jj < 4; jj++) {
      int n = n0 + tx * 4 + jj;
      Y[(m0 + ty * 4 + i) * 512 + n] = acc[i][jj] + bias[n];
    }
}

// ---------------- batchnorm over batch dim (in-place), optional relu
__global__ __launch_bounds__(256) void bn_kernel(float* __restrict__ Y,
    const float* __restrict__ gam, const float* __restrict__ bet, int relu) {
  const int cx = threadIdx.x & 15;
  const int rg = threadIdx.x >> 4;
  const int col = blockIdx.x * 16 + cx;
  __shared__ float rs[16 * 17], rs2[16 * 17];
  float s = 0.f, s2 = 0.f;
#pragma unroll
  for (int i = 0; i < 8; i++) {
    float v = Y[(rg * 8 + i) * 512 + col];
    s += v; s2 += v * v;
  }
  rs[rg * 17 + cx] = s;
  rs2[rg * 17 + cx] = s2;
  __syncthreads();
  if (threadIdx.x < 16) {
    float S = 0.f, S2 = 0.f;
#pragma unroll
    for (int q = 0; q < 16; q++) { S += rs[q * 17 + threadIdx.x]; S2 += rs2[q * 17 + threadIdx.x]; }
    float mean = S / 128.f;
    float var = S2 / 128.f - mean * mean;
    rs[threadIdx.x] = mean;
    rs2[threadIdx.x] = rsqrtf(var + 1e-5f);
  }
  __syncthreads();
  float mean = rs[cx], rstd = rs2[cx];
  float gv = gam[col], bv = bet[col];
#pragma unroll
  for (int i = 0; i < 8; i++) {
    int idx = (rg * 8 + i) * 512 + col;
    float v = (Y[idx] - mean) * rstd * gv + bv;
    if (relu) v = fmaxf(v, 0.f);
    Y[idx] = v;
  }
}

extern "C" void kernel_launch(void* const* d_in, const int* in_sizes, int n_in,
                              void* d_out, int out_size, void* d_ws, size_t ws_size,
                              hipStream_t stream) {
  const int* label      = (const int*)d_in[0];
  const int* label_len  = (const int*)d_in[1];
  const float* embed_w  = (const float*)d_in[2];
  const float* i2h_w    = (const float*)d_in[3];
  const float* i2h_b    = (const float*)d_in[4];
  const float* h2h_w    = (const float*)d_in[5];
  const float* h2h_b    = (const float*)d_in[6];
  const float* lin0_w   = (const float*)d_in[7];
  const float* lin0_b   = (const float*)d_in[8];
  const float* bn0_g    = (const float*)d_in[9];
  const float* bn0_b    = (const float*)d_in[10];
  const float* lin1_w   = (const float*)d_in[11];
  const float* lin1_b   = (const float*)d_in[12];
  const float* bn1_g    = (const float*)d_in[13];
  const float* bn1_b    = (const float*)d_in[14];
  float* out = (float*)d_out;
  char* ws = (char*)d_ws;

  const size_t OFF_FLAGS = 0;                                      // 16 KB
  const size_t OFF_I2H  = 16384;
  const size_t OFF_PRE  = OFF_I2H + (size_t)2560 * 512 * 2;        // fp16 i2h
  const size_t OFF_H    = OFF_PRE + (size_t)512 * 128 * 2560;      // int8 pre
  const size_t OFF_XSEL = OFF_H + (size_t)2 * 128 * 512 * 2;       // fp16 hfrag
  const size_t OFF_Y0   = OFF_XSEL + (size_t)128 * 512 * 4;

  int* flags = (int*)(ws + OFF_FLAGS);
  _Float16* i2h_h = (_Float16*)(ws + OFF_I2H);
  signed char* pre8 = (signed char*)(ws + OFF_PRE);
  _Float16* hfrag = (_Float16*)(ws + OFF_H);
  float* xsel = (float*)(ws + OFF_XSEL);
  float* y0   = (float*)(ws + OFF_Y0);

  hipMemsetAsync(ws + OFF_FLAGS, 0, 16384, stream);

  {
    int n4 = (2560 * 512) / 4;
    f2h_kernel<<<(n4 + 255) / 256, 256, 0, stream>>>(i2h_w, i2h_h, n4);
  }
  gemm1_kernel<<<dim3(20, 512), 256, 0, stream>>>(label, label_len, embed_w, i2h_h, pre8);
  lstm_kernel<<<dim3(1024), 256, 0, stream>>>(label_len, h2h_w, h2h_b, i2h_b, pre8, hfrag, xsel, flags);
  fgemm_kernel<<<dim3(8, 2), 256, 0, stream>>>(xsel, lin0_w, lin0_b, y0);
  bn_kernel<<<dim3(32), 256, 0, stream>>>(y0, bn0_g, bn0_b, 1);
  fgemm_kernel<<<dim3(8, 2), 256, 0, stream>>>(y0, lin1_w, lin1_b, out);
  bn_kernel<<<dim3(32), 256, 0, stream>>>(out, bn1_g, bn1_b, 0);
}

// Round 6
// 4518.446 us; speedup vs baseline: 729.0259x; 729.0259x over previous
//
#include <hip/hip_runtime.h>

typedef _Float16 h16x8 __attribute__((ext_vector_type(8)));
typedef _Float16 h16x4 __attribute__((ext_vector_type(4)));
typedef float fx4 __attribute__((ext_vector_type(4)));
typedef unsigned int u32x4 __attribute__((ext_vector_type(4)));
typedef unsigned long long ull;

// V=32001 E=512 H=512 LE=512 B=128 T=512, 5H=2560
#define PRE_S 2560.0f
#define PRE_INV (1.0f / 2560.0f)

// ---------------- fp32 -> fp16 bulk convert (i2h weights) ----------------
__global__ __launch_bounds__(256) void f2h_kernel(const float* __restrict__ src,
                                                  _Float16* __restrict__ dst,
                                                  int n4) {
  int i = blockIdx.x * 256 + threadIdx.x;
  if (i < n4) {
    float4 v = ((const float4*)src)[i];
    h16x4 o = {(_Float16)v.x, (_Float16)v.y, (_Float16)v.z, (_Float16)v.w};
    *(h16x4*)&dst[i * 4] = o;
  }
}

// ---------------- pre = gather(embed) @ i2h_w^T, int8 out (x2560 scale)
// pre8 layout (coalesced writes): pre8[t][j=64][b=128][g=5][u=8]
__global__ __launch_bounds__(256) void gemm1_kernel(
    const int* __restrict__ label, const int* __restrict__ label_len,
    const float* __restrict__ embed_w,        // fp32 [32001][512]
    const _Float16* __restrict__ Bh,          // i2h fp16 [2560][512]
    signed char* __restrict__ pre8) {
  const int bx = blockIdx.x;          // N tile 0..19
  const int by = blockIdx.y;          // M tile 0..511
  const int bidx = by >> 2;           // batch
  const int t0 = (by & 3) * 128;      // t range start
  if (t0 > label_len[bidx]) return;   // this tile's pre is never read

  const int tid = threadIdx.x;
  const int lane = tid & 63;
  const int wv = tid >> 6;
  const int wm = (wv & 1) * 64;
  const int wn = (wv >> 1) * 64;

  __shared__ _Float16 As[128 * 40];
  __shared__ _Float16 Bs[128 * 40];

  fx4 zero = {0.f, 0.f, 0.f, 0.f};
  fx4 acc[4][4];
  for (int a = 0; a < 4; a++)
    for (int b = 0; b < 4; b++) acc[a][b] = zero;

#pragma unroll 1
  for (int k0 = 0; k0 < 512; k0 += 32) {
#pragma unroll
    for (int q = 0; q < 2; q++) {
      int chunk = tid + q * 256;
      int row = chunk >> 2;
      int ko = (chunk & 3) * 8;
      int arow = label[bidx * 512 + t0 + row];
      const float* ap = &embed_w[(size_t)arow * 512 + k0 + ko];
      float4 a0 = *(const float4*)ap;
      float4 a1 = *(const float4*)(ap + 4);
      h16x8 av = {(_Float16)a0.x, (_Float16)a0.y, (_Float16)a0.z, (_Float16)a0.w,
                  (_Float16)a1.x, (_Float16)a1.y, (_Float16)a1.z, (_Float16)a1.w};
      h16x8 bv = *(const h16x8*)&Bh[(size_t)(bx * 128 + row) * 512 + k0 + ko];
      *(h16x8*)&As[row * 40 + ko] = av;
      *(h16x8*)&Bs[row * 40 + ko] = bv;
    }
    __syncthreads();
    h16x8 af[4], bfr[4];
#pragma unroll
    for (int i = 0; i < 4; i++) {
      af[i]  = *(const h16x8*)&As[(wm + i * 16 + (lane & 15)) * 40 + (lane >> 4) * 8];
      bfr[i] = *(const h16x8*)&Bs[(wn + i * 16 + (lane & 15)) * 40 + (lane >> 4) * 8];
    }
#pragma unroll
    for (int mi = 0; mi < 4; mi++)
#pragma unroll
      for (int ni = 0; ni < 4; ni++)
        acc[mi][ni] = __builtin_amdgcn_mfma_f32_16x16x32_f16(af[mi], bfr[ni], acc[mi][ni], 0, 0, 0);
    __syncthreads();
  }

#pragma unroll
  for (int mi = 0; mi < 4; mi++)
#pragma unroll
    for (int ni = 0; ni < 4; ni++)
#pragma unroll
      for (int r = 0; r < 4; r++) {
        int rowm = wm + mi * 16 + (lane >> 4) * 4 + r;
        int t = t0 + rowm;
        int n = bx * 128 + wn + ni * 16 + (lane & 15);
        float v = acc[mi][ni][r] * PRE_S;
        int q = (int)rintf(v);
        q = q > 127 ? 127 : (q < -127 ? -127 : q);
        int g = n >> 9, ju = n & 511, j = ju >> 3, uu = ju & 7;
        pre8[(((size_t)t * 64 + j) * 128 + bidx) * 40 + g * 8 + uu] = (signed char)q;
      }
}

// ---------------- persistent LSTM scan: tagged-data exchange, zero barriers.
// 64 WGs = 2 independent 32-WG groups (verified topology from round 1).
// GEMM operands SWAPPED vs round 1: A = W (stationary, LDS), B = h (dynamic).
// C-fragment: col=lane&15 = batch, row=(lane>>4)*4+r = unit -> each thread owns
// (4 units x 1 batch x 5 gates) fully in-register, which is EXACTLY the shape
// of the next step's B-fragment k-chunk. So the gate phase stores h directly as
// one 16B packet {tag, 4xfp16 h, tag} (double-ended tags detect any contiguous
// split of the store) -- no LDS repack, no __syncthreads, no drain, no flag.
// Consumers poll their own 32 data slots until tags==t. Wave b of every WG
// exchanges only batch-rows [16b,16b+16) with wave b of other WGs: 4 decoupled
// 32-wave chains per batch-half, zero per-step intra-WG sync.
// Backpressure: producer stores h(t+2) over h(t)'s slot only after its poll saw
// all tags t+2, which implies every reader of tag-t+1 data finished its GEMM.
// h buffer: [2 parity][128 batch][128 slots][16B] = 512 KB, memset 0 (tags>=1).
// Poll bound 1024 rounds: protocol failure degrades to a fast wrong-numerics
// run WITH counters, never a wedged container.
#define HROW 2048                 // 128 slots * 16B per batch row
#define POFF (128 * HROW)         // parity offset (256 KB)
__global__ __launch_bounds__(256, 1) void lstm_kernel(
    const int* __restrict__ label_len,
    const float* __restrict__ h2h_w,   // [2560][512] fp32
    const float* __restrict__ h2h_b,   // [2560]
    const float* __restrict__ i2h_b,   // [2560]
    const signed char* __restrict__ pre8,    // [512][64][128][5][8] int8
    char* __restrict__ hbuf,                 // [2][128][128][16] tagged h
    float* __restrict__ xsel) {              // [128][512] fp32
  const int jj  = blockIdx.x >> 1;    // unit tile 0..31
  const int bh  = blockIdx.x & 1;
  const int tid = threadIdx.x;
  const int lane = tid & 63;
  const int wv = tid >> 6;

  __shared__ _Float16 Wl[5 * 16 * 64 * 8];   // 80 KB, MFMA A-operand order
  __shared__ int ll_s[64];

  // stage h2h weights: m-tile g = gate, row-within-tile = unit (lane&15)
  for (int slot = tid; slot < 5 * 16 * 64; slot += 256) {
    int nt = slot >> 10;             // /(16*64)
    int rem = slot & 1023;
    int kt = rem >> 6;
    int l = rem & 63;
    int r = nt * 512 + jj * 16 + (l & 15);
    int k0 = kt * 32 + (l >> 4) * 8;
    const float* src = h2h_w + (size_t)r * 512 + k0;
    h16x8 tv;
#pragma unroll
    for (int q = 0; q < 8; q++) tv[q] = (_Float16)src[q];
    *(h16x8*)&Wl[slot * 8] = tv;
  }
  if (tid < 64) ll_s[tid] = label_len[bh * 64 + tid];
  __syncthreads();                   // the ONLY barrier in this kernel

  int tmax = 0;
#pragma unroll 1
  for (int i = 0; i < 64; i++) tmax = max(tmax, ll_s[i]);
  tmax += 1;

  // thread ownership from the C-fragment: units u4..u4+3, batch nb
  const int u4  = (lane >> 4) * 4;
  const int nb  = wv * 16 + (lane & 15);
  const int nbg = bh * 64 + nb;
  const int ll_r = ll_s[nb];

  float bias_r[5][4];
#pragma unroll
  for (int g = 0; g < 5; g++)
#pragma unroll
    for (int r = 0; r < 4; r++)
      bias_r[g][r] = h2h_b[g * 512 + jj * 16 + u4 + r]
                   + i2h_b[g * 512 + jj * 16 + u4 + r];

  // consumer base: batch row nb, k-chunk (lane>>4)*8 units -> +kt*128 bytes
  const char* cb = hbuf + (size_t)nbg * HROW + (lane >> 4) * 32;
  // producer slot: batch row nb, units jj*16+u4 -> slot (jj*4 + (lane>>4))
  char* pdst = hbuf + (size_t)nbg * HROW + (size_t)(jj * 64 + (lane >> 4) * 16);

  float c_reg[4] = {0.f, 0.f, 0.f, 0.f};

#pragma unroll 1
  for (int t = 0; t < tmax; ++t) {
    // pre8 prefetch: 5 gates x 4 units x 1 batch = 5 x 4B loads (plain cached)
    unsigned int pr[5];
    {
      const signed char* pt = pre8
          + ((size_t)(t * 64 + jj * 2 + (u4 >> 3)) * 128 + nbg) * 40 + (u4 & 7);
#pragma unroll
      for (int g = 0; g < 5; g++)
        pr[g] = *(const unsigned int*)(pt + g * 8);
    }

    fx4 acc[5] = {};
    if (t > 0) {
      const char* cbp = cb + ((t - 1) & 1) * POFF;
      const unsigned int tagv = (unsigned int)t;
      u32x4 fa[16], fb[16];
      int rounds = 0;
      while (true) {
#pragma unroll
        for (int kt = 0; kt < 16; ++kt) {
          asm volatile("global_load_dwordx4 %0, %2, off sc0 sc1\n\t"
                       "global_load_dwordx4 %1, %2, off offset:16 sc0 sc1"
                       : "=v"(fa[kt]), "=v"(fb[kt])
                       : "v"((const void*)(cbp + kt * 128))
                       : "memory");
        }
        asm volatile("s_waitcnt vmcnt(0)" ::: "memory");
        int ok = 1;
#pragma unroll
        for (int kt = 0; kt < 16; ++kt)
          ok &= (fa[kt].x == tagv) & (fa[kt].w == tagv)
              & (fb[kt].x == tagv) & (fb[kt].w == tagv);
        if (__ballot(ok) == 0xFFFFFFFFFFFFFFFFull) break;
        if (++rounds > 1024) break;   // bounded: degrade, don't hang
        __builtin_amdgcn_s_sleep(1);  // back off the LLC between rounds
      }
      __builtin_amdgcn_sched_barrier(0);

      // GEMM: A = W from LDS, B = h from the freshly polled registers
#pragma unroll
      for (int kt = 0; kt < 16; ++kt) {
        union { unsigned int u[4]; h16x8 h; } hh;
        hh.u[0] = fa[kt].y; hh.u[1] = fa[kt].z;
        hh.u[2] = fb[kt].y; hh.u[3] = fb[kt].z;
#pragma unroll
        for (int g = 0; g < 5; ++g) {
          h16x8 wf = *(const h16x8*)&Wl[((g * 16 + kt) * 64 + lane) * 8];
          acc[g] = __builtin_amdgcn_mfma_f32_16x16x32_f16(wf, hh.h, acc[g], 0, 0, 0);
        }
      }
    }

    // gates fully in-register: acc[g][r] = s_gate[unit u4+r][batch nb]
    float nh4[4];
#pragma unroll
    for (int r = 0; r < 4; ++r) {
      float sv[5];
#pragma unroll
      for (int g = 0; g < 5; g++) {
        signed char qb = (signed char)((pr[g] >> (8 * r)) & 0xFF);
        sv[g] = acc[g][r] + (float)qb * PRE_INV + bias_r[g][r];
      }
      float ing = __builtin_amdgcn_rcpf(1.f + __expf(-sv[0]));
      float fg  = __builtin_amdgcn_rcpf(1.f + __expf(-sv[1]));
      float og  = __builtin_amdgcn_rcpf(1.f + __expf(-sv[2]));
      float itv = fmaxf(sv[3], sv[4]);
      float nc  = fg * c_reg[r] + ing * itv;
      c_reg[r] = nc;
      nh4[r] = og * (1.f - 2.f * __builtin_amdgcn_rcpf(__expf(2.f * nc) + 1.f));
    }

    // single 16B tagged store: {tag, h x4 fp16, tag} -- readiness IS the data
    {
      union { struct { unsigned int t0; _Float16 h[4]; unsigned int t1; } s;
              u32x4 v; } pk;
      pk.s.t0 = (unsigned int)(t + 1);
      pk.s.t1 = (unsigned int)(t + 1);
#pragma unroll
      for (int r = 0; r < 4; ++r) pk.s.h[r] = (_Float16)nh4[r];
      char* dp = pdst + (t & 1) * POFF;
      asm volatile("global_store_dwordx4 %0, %1, off sc0 sc1"
                   :: "v"(dp), "v"(pk.v) : "memory");
    }

    if (ll_r == t) {
      fx4 o = {nh4[0], nh4[1], nh4[2], nh4[3]};
      *(fx4*)&xsel[(size_t)nbg * 512 + jj * 16 + u4] = o;
    }
  }
}

// ---------------- small fp32 GEMM: Y[128,512] = X[128,512] @ W[512,512]^T + bias
__global__ __launch_bounds__(256) void fgemm_kernel(
    const float* __restrict__ X, const float* __restrict__ W,
    const float* __restrict__ bias, float* __restrict__ Y) {
  const int n0 = blockIdx.x * 64;
  const int m0 = blockIdx.y * 64;
  const int tid = threadIdx.x;
  const int tx = tid & 15, ty = tid >> 4;

  __shared__ float Xs[64 * 68];
  __shared__ float Wt[64 * 68];

  float acc[4][4] = {};
#pragma unroll 1
  for (int k0 = 0; k0 < 512; k0 += 64) {
#pragma unroll
    for (int q = 0; q < 4; q++) {
      int id = tid + q * 256;
      int r = id >> 4, c = id & 15;
      float4 xv = *(const float4*)&X[(m0 + r) * 512 + k0 + c * 4];
      *(float4*)&Xs[r * 68 + c * 4] = xv;
      float4 wvv = *(const float4*)&W[(n0 + r) * 512 + k0 + c * 4];
      Wt[(c * 4 + 0) * 68 + r] = wvv.x;
      Wt[(c * 4 + 1) * 68 + r] = wvv.y;
      Wt[(c * 4 + 2) * 68 + r] = wvv.z;
      Wt[(c * 4 + 3) * 68 + r] = wvv.w;
    }
    __syncthreads();
#pragma unroll 4
    for (int kk = 0; kk < 64; kk++) {
      float a[4], b[4];
#pragma unroll
      for (int i = 0; i < 4; i++) a[i] = Xs[(ty * 4 + i) * 68 + kk];
#pragma unroll
      for (int jj = 0; jj < 4; jj++) b[jj] = Wt[kk * 68 + tx * 4 + jj];
#pragma unroll
      for (int i = 0; i < 4; i++)
#pragma unroll
        for (int jj = 0; jj < 4; jj++) acc[i][jj] += a[i] * b[jj];
    }
    __syncthreads();
  }
#pragma unroll
  for (int i = 0; i < 4; i++)
#pragma unroll
    for (int jj = 0; jj < 4; jj++) {
      int n = n0 + tx * 4 + jj;
      Y[(m0 + ty * 4 + i) * 512 + n] = acc[i][jj] + bias[n];
    }
}

// ---------------- batchnorm over batch dim (in-place), optional relu
__global__ __launch_bounds__(256) void bn_kernel(float* __restrict__ Y,
    const float* __restrict__ gam, const float* __restrict__ bet, int relu) {
  const int cx = threadIdx.x & 15;
  const int rg = threadIdx.x >> 4;
  const int col = blockIdx.x * 16 + cx;
  __shared__ float rs[16 * 17], rs2[16 * 17];
  float s = 0.f, s2 = 0.f;
#pragma unroll
  for (int i = 0; i < 8; i++) {
    float v = Y[(rg * 8 + i) * 512 + col];
    s += v; s2 += v * v;
  }
  rs[rg * 17 + cx] = s;
  rs2[rg * 17 + cx] = s2;
  __syncthreads();
  if (threadIdx.x < 16) {
    float S = 0.f, S2 = 0.f;
#pragma unroll
    for (int q = 0; q < 16; q++) { S += rs[q * 17 + threadIdx.x]; S2 += rs2[q * 17 + threadIdx.x]; }
    float mean = S / 128.f;
    float var = S2 / 128.f - mean * mean;
    rs[threadIdx.x] = mean;
    rs2[threadIdx.x] = rsqrtf(var + 1e-5f);
  }
  __syncthreads();
  float mean = rs[cx], rstd = rs2[cx];
  float gv = gam[col], bv = bet[col];
#pragma unroll
  for (int i = 0; i < 8; i++) {
    int idx = (rg * 8 + i) * 512 + col;
    float v = (Y[idx] - mean) * rstd * gv + bv;
    if (relu) v = fmaxf(v, 0.f);
    Y[idx] = v;
  }
}

extern "C" void kernel_launch(void* const* d_in, const int* in_sizes, int n_in,
                              void* d_out, int out_size, void* d_ws, size_t ws_size,
                              hipStream_t stream) {
  const int* label      = (const int*)d_in[0];
  const int* label_len  = (const int*)d_in[1];
  const float* embed_w  = (const float*)d_in[2];
  const float* i2h_w    = (const float*)d_in[3];
  const float* i2h_b    = (const float*)d_in[4];
  const float* h2h_w    = (const float*)d_in[5];
  const float* h2h_b    = (const float*)d_in[6];
  const float* lin0_w   = (const float*)d_in[7];
  const float* lin0_b   = (const float*)d_in[8];
  const float* bn0_g    = (const float*)d_in[9];
  const float* bn0_b    = (const float*)d_in[10];
  const float* lin1_w   = (const float*)d_in[11];
  const float* lin1_b   = (const float*)d_in[12];
  const float* bn1_g    = (const float*)d_in[13];
  const float* bn1_b    = (const float*)d_in[14];
  float* out = (float*)d_out;
  char* ws = (char*)d_ws;

  const size_t OFF_I2H  = 0;                                       // fp16 i2h
  const size_t OFF_PRE  = OFF_I2H + (size_t)2560 * 512 * 2;        // int8 pre
  const size_t OFF_H    = OFF_PRE + (size_t)512 * 128 * 2560;      // tagged h
  const size_t OFF_XSEL = OFF_H + (size_t)2 * 128 * 128 * 16;      // 512 KB h
  const size_t OFF_Y0   = OFF_XSEL + (size_t)128 * 512 * 4;

  _Float16* i2h_h = (_Float16*)(ws + OFF_I2H);
  signed char* pre8 = (signed char*)(ws + OFF_PRE);
  char* hbuf = ws + OFF_H;
  float* xsel = (float*)(ws + OFF_XSEL);
  float* y0   = (float*)(ws + OFF_Y0);

  hipMemsetAsync(hbuf, 0, (size_t)2 * 128 * 128 * 16, stream);

  {
    int n4 = (2560 * 512) / 4;
    f2h_kernel<<<(n4 + 255) / 256, 256, 0, stream>>>(i2h_w, i2h_h, n4);
  }
  gemm1_kernel<<<dim3(20, 512), 256, 0, stream>>>(label, label_len, embed_w, i2h_h, pre8);
  lstm_kernel<<<dim3(64), 256, 0, stream>>>(label_len, h2h_w, h2h_b, i2h_b, pre8, hbuf, xsel);
  fgemm_kernel<<<dim3(8, 2), 256, 0, stream>>>(xsel, lin0_w, lin0_b, y0);
  bn_kernel<<<dim3(32), 256, 0, stream>>>(y0, bn0_g, bn0_b, 1);
  fgemm_kernel<<<dim3(8, 2), 256, 0, stream>>>(y0, lin1_w, lin1_b, out);
  bn_kernel<<<dim3(32), 256, 0, stream>>>(out, bn1_g, bn1_b, 0);
}

// Round 7
// 2789.425 us; speedup vs baseline: 1180.9116x; 1.6198x over previous
//
#include <hip/hip_runtime.h>

typedef _Float16 h16x8 __attribute__((ext_vector_type(8)));
typedef _Float16 h16x4 __attribute__((ext_vector_type(4)));
typedef float fx4 __attribute__((ext_vector_type(4)));
typedef unsigned int u32x4 __attribute__((ext_vector_type(4)));
typedef unsigned long long ull;

// V=32001 E=512 H=512 LE=512 B=128 T=512, 5H=2560
#define PRE_S 2560.0f
#define PRE_INV (1.0f / 2560.0f)

// ---------------- fp32 -> fp16 bulk convert (i2h weights) ----------------
__global__ __launch_bounds__(256) void f2h_kernel(const float* __restrict__ src,
                                                  _Float16* __restrict__ dst,
                                                  int n4) {
  int i = blockIdx.x * 256 + threadIdx.x;
  if (i < n4) {
    float4 v = ((const float4*)src)[i];
    h16x4 o = {(_Float16)v.x, (_Float16)v.y, (_Float16)v.z, (_Float16)v.w};
    *(h16x4*)&dst[i * 4] = o;
  }
}

// ---------------- pre = gather(embed) @ i2h_w^T, int8 out (x2560 scale)
// pre8 layout (coalesced writes): pre8[t][j=64][b=128][g=5][u=8]
__global__ __launch_bounds__(256) void gemm1_kernel(
    const int* __restrict__ label, const int* __restrict__ label_len,
    const float* __restrict__ embed_w,        // fp32 [32001][512]
    const _Float16* __restrict__ Bh,          // i2h fp16 [2560][512]
    signed char* __restrict__ pre8) {
  const int bx = blockIdx.x;          // N tile 0..19
  const int by = blockIdx.y;          // M tile 0..511
  const int bidx = by >> 2;           // batch
  const int t0 = (by & 3) * 128;      // t range start
  if (t0 > label_len[bidx]) return;   // this tile's pre is never read

  const int tid = threadIdx.x;
  const int lane = tid & 63;
  const int wv = tid >> 6;
  const int wm = (wv & 1) * 64;
  const int wn = (wv >> 1) * 64;

  __shared__ _Float16 As[128 * 40];
  __shared__ _Float16 Bs[128 * 40];

  fx4 zero = {0.f, 0.f, 0.f, 0.f};
  fx4 acc[4][4];
  for (int a = 0; a < 4; a++)
    for (int b = 0; b < 4; b++) acc[a][b] = zero;

#pragma unroll 1
  for (int k0 = 0; k0 < 512; k0 += 32) {
#pragma unroll
    for (int q = 0; q < 2; q++) {
      int chunk = tid + q * 256;
      int row = chunk >> 2;
      int ko = (chunk & 3) * 8;
      int arow = label[bidx * 512 + t0 + row];
      const float* ap = &embed_w[(size_t)arow * 512 + k0 + ko];
      float4 a0 = *(const float4*)ap;
      float4 a1 = *(const float4*)(ap + 4);
      h16x8 av = {(_Float16)a0.x, (_Float16)a0.y, (_Float16)a0.z, (_Float16)a0.w,
                  (_Float16)a1.x, (_Float16)a1.y, (_Float16)a1.z, (_Float16)a1.w};
      h16x8 bv = *(const h16x8*)&Bh[(size_t)(bx * 128 + row) * 512 + k0 + ko];
      *(h16x8*)&As[row * 40 + ko] = av;
      *(h16x8*)&Bs[row * 40 + ko] = bv;
    }
    __syncthreads();
    h16x8 af[4], bfr[4];
#pragma unroll
    for (int i = 0; i < 4; i++) {
      af[i]  = *(const h16x8*)&As[(wm + i * 16 + (lane & 15)) * 40 + (lane >> 4) * 8];
      bfr[i] = *(const h16x8*)&Bs[(wn + i * 16 + (lane & 15)) * 40 + (lane >> 4) * 8];
    }
#pragma unroll
    for (int mi = 0; mi < 4; mi++)
#pragma unroll
      for (int ni = 0; ni < 4; ni++)
        acc[mi][ni] = __builtin_amdgcn_mfma_f32_16x16x32_f16(af[mi], bfr[ni], acc[mi][ni], 0, 0, 0);
    __syncthreads();
  }

#pragma unroll
  for (int mi = 0; mi < 4; mi++)
#pragma unroll
    for (int ni = 0; ni < 4; ni++)
#pragma unroll
      for (int r = 0; r < 4; r++) {
        int rowm = wm + mi * 16 + (lane >> 4) * 4 + r;
        int t = t0 + rowm;
        int n = bx * 128 + wn + ni * 16 + (lane & 15);
        float v = acc[mi][ni][r] * PRE_S;
        int q = (int)rintf(v);
        q = q > 127 ? 127 : (q < -127 ? -127 : q);
        int g = n >> 9, ju = n & 511, j = ju >> 3, uu = ju & 7;
        pre8[(((size_t)t * 64 + j) * 128 + bidx) * 40 + g * 8 + uu] = (signed char)q;
      }
}

// ---------------- persistent LSTM scan: tagged-data exchange, zero barriers.
// 64 WGs = 2 independent 32-WG groups. Identical to round 6 EXCEPT the mailbox
// layout, which eliminates 128B-line false sharing (round 6's diagnosed 2x):
//   mail[parity][bh][jj=32][wv=4][lane=64][16B packet]
// A producer wave's 64 packets are 1KB contiguous, line-aligned -> each 128B
// line is written by ONE wave in ONE coalesced burst, so lines become fresh
// atomically at the LLC instead of accumulating 8 independent WGs' sectors
// under reader ping-pong. Packet = {tag, tag, 4xfp16 h} (16B store is single-
// instruction; tag duplicated only to fill the dword). Consumer (wave wv,
// batch nb=wv*16+(lane&15), k-slice (lane>>4)*8) reads per kt two packets of
// producer jj=2kt+(lane>>5): lp and lp+16 (offset:256 pair).
// Backpressure unchanged (2-step-lead proof, HW-validated in round 6).
// Poll bound 2048 rounds: degrade, never hang.
#define MAILBH 131072             // bytes per bh half (8192 packets)
#define POFF   262144             // parity offset (2 bh halves)
__global__ __launch_bounds__(256, 1) void lstm_kernel(
    const int* __restrict__ label_len,
    const float* __restrict__ h2h_w,   // [2560][512] fp32
    const float* __restrict__ h2h_b,   // [2560]
    const float* __restrict__ i2h_b,   // [2560]
    const signed char* __restrict__ pre8,    // [512][64][128][5][8] int8
    char* __restrict__ hbuf,                 // [2][2][32][4][64][16] tagged h
    float* __restrict__ xsel) {              // [128][512] fp32
  const int jj  = blockIdx.x >> 1;    // unit tile 0..31
  const int bh  = blockIdx.x & 1;
  const int tid = threadIdx.x;
  const int lane = tid & 63;
  const int wv = tid >> 6;

  __shared__ _Float16 Wl[5 * 16 * 64 * 8];   // 80 KB, MFMA A-operand order
  __shared__ int ll_s[64];

  // stage h2h weights: m-tile g = gate, row-within-tile = unit (lane&15)
  for (int slot = tid; slot < 5 * 16 * 64; slot += 256) {
    int nt = slot >> 10;             // /(16*64)
    int rem = slot & 1023;
    int kt = rem >> 6;
    int l = rem & 63;
    int r = nt * 512 + jj * 16 + (l & 15);
    int k0 = kt * 32 + (l >> 4) * 8;
    const float* src = h2h_w + (size_t)r * 512 + k0;
    h16x8 tv;
#pragma unroll
    for (int q = 0; q < 8; q++) tv[q] = (_Float16)src[q];
    *(h16x8*)&Wl[slot * 8] = tv;
  }
  if (tid < 64) ll_s[tid] = label_len[bh * 64 + tid];
  __syncthreads();                   // the ONLY barrier in this kernel

  int tmax = 0;
#pragma unroll 1
  for (int i = 0; i < 64; i++) tmax = max(tmax, ll_s[i]);
  tmax += 1;

  // thread ownership from the C-fragment: units u4..u4+3, batch nb
  const int u4  = (lane >> 4) * 4;
  const int nb  = wv * 16 + (lane & 15);
  const int nbg = bh * 64 + nb;
  const int ll_r = ll_s[nb];

  float bias_r[5][4];
#pragma unroll
  for (int g = 0; g < 5; g++)
#pragma unroll
    for (int r = 0; r < 4; r++)
      bias_r[g][r] = h2h_b[g * 512 + jj * 16 + u4 + r]
                   + i2h_b[g * 512 + jj * 16 + u4 + r];

  // producer packet: mail[bh][jj][wv][lane] (wave = 1KB contiguous burst)
  char* pdst = hbuf + bh * MAILBH + (size_t)(((jj * 4 + wv) * 64) + lane) * 16;
  // consumer base: per kt reads packets lp, lp+16 of producer jj=2kt+(lane>>5)
  const char* cb0 = hbuf + bh * MAILBH
                  + (size_t)(lane >> 5) * 4096 + (size_t)wv * 1024
                  + (size_t)((lane >> 4) & 1) * 512 + (size_t)(lane & 15) * 16;

  float c_reg[4] = {0.f, 0.f, 0.f, 0.f};

#pragma unroll 1
  for (int t = 0; t < tmax; ++t) {
    // pre8 prefetch: 5 gates x 4 units x 1 batch (plain cached loads)
    unsigned int pr[5];
    {
      const signed char* pt = pre8
          + ((size_t)(t * 64 + jj * 2 + (u4 >> 3)) * 128 + nbg) * 40 + (u4 & 7);
#pragma unroll
      for (int g = 0; g < 5; g++)
        pr[g] = *(const unsigned int*)(pt + g * 8);
    }

    fx4 acc[5] = {};
    if (t > 0) {
      const char* cbp = cb0 + ((t - 1) & 1) * POFF;
      const unsigned int tagv = (unsigned int)t;
      u32x4 f0[16], f1[16];
      int rounds = 0;
      while (true) {
#pragma unroll
        for (int kt = 0; kt < 16; ++kt) {
          const void* ap = (const void*)(cbp + kt * 8192);
          asm volatile("global_load_dwordx4 %0, %2, off sc0 sc1\n\t"
                       "global_load_dwordx4 %1, %2, off offset:256 sc0 sc1"
                       : "=v"(f0[kt]), "=v"(f1[kt]) : "v"(ap) : "memory");
        }
        asm volatile("s_waitcnt vmcnt(0)" ::: "memory");
        int ok = 1;
#pragma unroll
        for (int kt = 0; kt < 16; ++kt)
          ok &= (f0[kt].x == tagv) & (f1[kt].x == tagv);
        if (__ballot(ok) == 0xFFFFFFFFFFFFFFFFull) break;
        if (++rounds > 2048) break;   // bounded: degrade, don't hang
        __builtin_amdgcn_s_sleep(2);  // back off the LLC between rounds
      }
      __builtin_amdgcn_sched_barrier(0);

      // GEMM: A = W from LDS, B = h from the freshly polled registers
#pragma unroll
      for (int kt = 0; kt < 16; ++kt) {
        union { unsigned int u[4]; h16x8 h; } hh;
        hh.u[0] = f0[kt].z; hh.u[1] = f0[kt].w;
        hh.u[2] = f1[kt].z; hh.u[3] = f1[kt].w;
#pragma unroll
        for (int g = 0; g < 5; ++g) {
          h16x8 wf = *(const h16x8*)&Wl[((g * 16 + kt) * 64 + lane) * 8];
          acc[g] = __builtin_amdgcn_mfma_f32_16x16x32_f16(wf, hh.h, acc[g], 0, 0, 0);
        }
      }
    }

    // gates fully in-register: acc[g][r] = s_gate[unit u4+r][batch nb]
    float nh4[4];
#pragma unroll
    for (int r = 0; r < 4; ++r) {
      float sv[5];
#pragma unroll
      for (int g = 0; g < 5; g++) {
        signed char qb = (signed char)((pr[g] >> (8 * r)) & 0xFF);
        sv[g] = acc[g][r] + (float)qb * PRE_INV + bias_r[g][r];
      }
      float ing = __builtin_amdgcn_rcpf(1.f + __expf(-sv[0]));
      float fg  = __builtin_amdgcn_rcpf(1.f + __expf(-sv[1]));
      float og  = __builtin_amdgcn_rcpf(1.f + __expf(-sv[2]));
      float itv = fmaxf(sv[3], sv[4]);
      float nc  = fg * c_reg[r] + ing * itv;
      c_reg[r] = nc;
      nh4[r] = og * (1.f - 2.f * __builtin_amdgcn_rcpf(__expf(2.f * nc) + 1.f));
    }

    // single 16B tagged packet: {tag, tag, h x4 fp16} -- readiness IS the data
    {
      union { struct { unsigned int t0; unsigned int t1; _Float16 h[4]; } s;
              u32x4 v; } pk;
      pk.s.t0 = (unsigned int)(t + 1);
      pk.s.t1 = (unsigned int)(t + 1);
#pragma unroll
      for (int r = 0; r < 4; ++r) pk.s.h[r] = (_Float16)nh4[r];
      char* dp = pdst + (t & 1) * POFF;
      asm volatile("global_store_dwordx4 %0, %1, off sc0 sc1"
                   :: "v"(dp), "v"(pk.v) : "memory");
    }

    if (ll_r == t) {
      fx4 o = {nh4[0], nh4[1], nh4[2], nh4[3]};
      *(fx4*)&xsel[(size_t)nbg * 512 + jj * 16 + u4] = o;
    }
  }
}

// ---------------- small fp32 GEMM: Y[128,512] = X[128,512] @ W[512,512]^T + bias
__global__ __launch_bounds__(256) void fgemm_kernel(
    const float* __restrict__ X, const float* __restrict__ W,
    const float* __restrict__ bias, float* __restrict__ Y) {
  const int n0 = blockIdx.x * 64;
  const int m0 = blockIdx.y * 64;
  const int tid = threadIdx.x;
  const int tx = tid & 15, ty = tid >> 4;

  __shared__ float Xs[64 * 68];
  __shared__ float Wt[64 * 68];

  float acc[4][4] = {};
#pragma unroll 1
  for (int k0 = 0; k0 < 512; k0 += 64) {
#pragma unroll
    for (int q = 0; q < 4; q++) {
      int id = tid + q * 256;
      int r = id >> 4, c = id & 15;
      float4 xv = *(const float4*)&X[(m0 + r) * 512 + k0 + c * 4];
      *(float4*)&Xs[r * 68 + c * 4] = xv;
      float4 wvv = *(const float4*)&W[(n0 + r) * 512 + k0 + c * 4];
      Wt[(c * 4 + 0) * 68 + r] = wvv.x;
      Wt[(c * 4 + 1) * 68 + r] = wvv.y;
      Wt[(c * 4 + 2) * 68 + r] = wvv.z;
      Wt[(c * 4 + 3) * 68 + r] = wvv.w;
    }
    __syncthreads();
#pragma unroll 4
    for (int kk = 0; kk < 64; kk++) {
      float a[4], b[4];
#pragma unroll
      for (int i = 0; i < 4; i++) a[i] = Xs[(ty * 4 + i) * 68 + kk];
#pragma unroll
      for (int jj = 0; jj < 4; jj++) b[jj] = Wt[kk * 68 + tx * 4 + jj];
#pragma unroll
      for (int i = 0; i < 4; i++)
#pragma unroll
        for (int jj = 0; jj < 4; jj++) acc[i][jj] += a[i] * b[jj];
    }
    __syncthreads();
  }
#pragma unroll
  for (int i = 0; i < 4; i++)
#pragma unroll
    for (int jj = 0; jj < 4; jj++) {
      int n = n0 + tx * 4 + jj;
      Y[(m0 + ty * 4 + i) * 512 + n] = acc[i][jj] + bias[n];
    }
}

// ---------------- batchnorm over batch dim (in-place), optional relu
__global__ __launch_bounds__(256) void bn_kernel(float* __restrict__ Y,
    const float* __restrict__ gam, const float* __restrict__ bet, int relu) {
  const int cx = threadIdx.x & 15;
  const int rg = threadIdx.x >> 4;
  const int col = blockIdx.x * 16 + cx;
  __shared__ float rs[16 * 17], rs2[16 * 17];
  float s = 0.f, s2 = 0.f;
#pragma unroll
  for (int i = 0; i < 8; i++) {
    float v = Y[(rg * 8 + i) * 512 + col];
    s += v; s2 += v * v;
  }
  rs[rg * 17 + cx] = s;
  rs2[rg * 17 + cx] = s2;
  __syncthreads();
  if (threadIdx.x < 16) {
    float S = 0.f, S2 = 0.f;
#pragma unroll
    for (int q = 0; q < 16; q++) { S += rs[q * 17 + threadIdx.x]; S2 += rs2[q * 17 + threadIdx.x]; }
    float mean = S / 128.f;
    float var = S2 / 128.f - mean * mean;
    rs[threadIdx.x] = mean;
    rs2[threadIdx.x] = rsqrtf(var + 1e-5f);
  }
  __syncthreads();
  float mean = rs[cx], rstd = rs2[cx];
  float gv = gam[col], bv = bet[col];
#pragma unroll
  for (int i = 0; i < 8; i++) {
    int idx = (rg * 8 + i) * 512 + col;
    float v = (Y[idx] - mean) * rstd * gv + bv;
    if (relu) v = fmaxf(v, 0.f);
    Y[idx] = v;
  }
}

extern "C" void kernel_launch(void* const* d_in, const int* in_sizes, int n_in,
                              void* d_out, int out_size, void* d_ws, size_t ws_size,
                              hipStream_t stream) {
  const int* label      = (const int*)d_in[0];
  const int* label_len  = (const int*)d_in[1];
  const float* embed_w  = (const float*)d_in[2];
  const float* i2h_w    = (const float*)d_in[3];
  const float* i2h_b    = (const float*)d_in[4];
  const float* h2h_w    = (const float*)d_in[5];
  const float* h2h_b    = (const float*)d_in[6];
  const float* lin0_w   = (const float*)d_in[7];
  const float* lin0_b   = (const float*)d_in[8];
  const float* bn0_g    = (const float*)d_in[9];
  const float* bn0_b    = (const float*)d_in[10];
  const float* lin1_w   = (const float*)d_in[11];
  const float* lin1_b   = (const float*)d_in[12];
  const float* bn1_g    = (const float*)d_in[13];
  const float* bn1_b    = (const float*)d_in[14];
  float* out = (float*)d_out;
  char* ws = (char*)d_ws;

  const size_t OFF_I2H  = 0;                                       // fp16 i2h
  const size_t OFF_PRE  = OFF_I2H + (size_t)2560 * 512 * 2;        // int8 pre
  const size_t OFF_H    = OFF_PRE + (size_t)512 * 128 * 2560;      // tagged h
  const size_t OFF_XSEL = OFF_H + (size_t)2 * 128 * 128 * 16;      // 512 KB h
  const size_t OFF_Y0   = OFF_XSEL + (size_t)128 * 512 * 4;

  _Float16* i2h_h = (_Float16*)(ws + OFF_I2H);
  signed char* pre8 = (signed char*)(ws + OFF_PRE);
  char* hbuf = ws + OFF_H;
  float* xsel = (float*)(ws + OFF_XSEL);
  float* y0   = (float*)(ws + OFF_Y0);

  hipMemsetAsync(hbuf, 0, (size_t)2 * 128 * 128 * 16, stream);

  {
    int n4 = (2560 * 512) / 4;
    f2h_kernel<<<(n4 + 255) / 256, 256, 0, stream>>>(i2h_w, i2h_h, n4);
  }
  gemm1_kernel<<<dim3(20, 512), 256, 0, stream>>>(label, label_len, embed_w, i2h_h, pre8);
  lstm_kernel<<<dim3(64), 256, 0, stream>>>(label_len, h2h_w, h2h_b, i2h_b, pre8, hbuf, xsel);
  fgemm_kernel<<<dim3(8, 2), 256, 0, stream>>>(xsel, lin0_w, lin0_b, y0);
  bn_kernel<<<dim3(32), 256, 0, stream>>>(y0, bn0_g, bn0_b, 1);
  fgemm_kernel<<<dim3(8, 2), 256, 0, stream>>>(y0, lin1_w, lin1_b, out);
  bn_kernel<<<dim3(32), 256, 0, stream>>>(out, bn1_g, bn1_b, 0);
}

// Round 8
// 2438.632 us; speedup vs baseline: 1350.7835x; 1.1438x over previous
//
#include <hip/hip_runtime.h>

typedef _Float16 h16x8 __attribute__((ext_vector_type(8)));
typedef _Float16 h16x4 __attribute__((ext_vector_type(4)));
typedef float fx4 __attribute__((ext_vector_type(4)));
typedef unsigned int u32x4 __attribute__((ext_vector_type(4)));
typedef unsigned long long ull;

// V=32001 E=512 H=512 LE=512 B=128 T=512, 5H=2560
#define PRE_S 2560.0f
#define PRE_INV (1.0f / 2560.0f)

// ---------------- fp32 -> fp16 bulk convert (i2h weights) ----------------
__global__ __launch_bounds__(256) void f2h_kernel(const float* __restrict__ src,
                                                  _Float16* __restrict__ dst,
                                                  int n4) {
  int i = blockIdx.x * 256 + threadIdx.x;
  if (i < n4) {
    float4 v = ((const float4*)src)[i];
    h16x4 o = {(_Float16)v.x, (_Float16)v.y, (_Float16)v.z, (_Float16)v.w};
    *(h16x4*)&dst[i * 4] = o;
  }
}

// ---------------- pre = gather(embed) @ i2h_w^T, int8 out (x2560 scale)
// pre8 layout wg-local: pre8[t][j][b][g][u]  (j=0..63, b=0..127, g=0..4, u=0..7)
__global__ __launch_bounds__(256) void gemm1_kernel(
    const int* __restrict__ label, const int* __restrict__ label_len,
    const float* __restrict__ embed_w,        // fp32 [32001][512]
    const _Float16* __restrict__ Bh,          // i2h fp16 [2560][512]
    signed char* __restrict__ pre8) {
  const int bx = blockIdx.x;          // N tile 0..19
  const int by = blockIdx.y;          // M tile 0..511
  const int bidx = by >> 2;           // batch
  const int t0 = (by & 3) * 128;      // t range start
  if (t0 > label_len[bidx]) return;   // this tile's pre is never read

  const int tid = threadIdx.x;
  const int lane = tid & 63;
  const int wv = tid >> 6;
  const int wm = (wv & 1) * 64;
  const int wn = (wv >> 1) * 64;

  __shared__ _Float16 As[128 * 40];
  __shared__ _Float16 Bs[128 * 40];

  fx4 zero = {0.f, 0.f, 0.f, 0.f};
  fx4 acc[4][4];
  for (int a = 0; a < 4; a++)
    for (int b = 0; b < 4; b++) acc[a][b] = zero;

#pragma unroll 1
  for (int k0 = 0; k0 < 512; k0 += 32) {
#pragma unroll
    for (int q = 0; q < 2; q++) {
      int chunk = tid + q * 256;
      int row = chunk >> 2;
      int ko = (chunk & 3) * 8;
      int arow = label[bidx * 512 + t0 + row];
      const float* ap = &embed_w[(size_t)arow * 512 + k0 + ko];
      float4 a0 = *(const float4*)ap;
      float4 a1 = *(const float4*)(ap + 4);
      h16x8 av = {(_Float16)a0.x, (_Float16)a0.y, (_Float16)a0.z, (_Float16)a0.w,
                  (_Float16)a1.x, (_Float16)a1.y, (_Float16)a1.z, (_Float16)a1.w};
      h16x8 bv = *(const h16x8*)&Bh[(size_t)(bx * 128 + row) * 512 + k0 + ko];
      *(h16x8*)&As[row * 40 + ko] = av;
      *(h16x8*)&Bs[row * 40 + ko] = bv;
    }
    __syncthreads();
    h16x8 af[4], bfr[4];
#pragma unroll
    for (int i = 0; i < 4; i++) {
      af[i]  = *(const h16x8*)&As[(wm + i * 16 + (lane & 15)) * 40 + (lane >> 4) * 8];
      bfr[i] = *(const h16x8*)&Bs[(wn + i * 16 + (lane & 15)) * 40 + (lane >> 4) * 8];
    }
#pragma unroll
    for (int mi = 0; mi < 4; mi++)
#pragma unroll
      for (int ni = 0; ni < 4; ni++)
        acc[mi][ni] = __builtin_amdgcn_mfma_f32_16x16x32_f16(af[mi], bfr[ni], acc[mi][ni], 0, 0, 0);
    __syncthreads();
  }

#pragma unroll
  for (int mi = 0; mi < 4; mi++)
#pragma unroll
    for (int ni = 0; ni < 4; ni++)
#pragma unroll
      for (int r = 0; r < 4; r++) {
        int rowm = wm + mi * 16 + (lane >> 4) * 4 + r;
        int t = t0 + rowm;
        int n = bx * 128 + wn + ni * 16 + (lane & 15);
        float v = acc[mi][ni][r] * PRE_S;
        int q = (int)rintf(v);
        q = q > 127 ? 127 : (q < -127 ? -127 : q);
        int g = n >> 9, ju = n & 511, j = ju >> 3, u = ju & 7;
        pre8[(((size_t)t * 64 + j) * 128 + bidx) * 40 + g * 8 + u] = (signed char)q;
      }
}

// ---------------- persistent LSTM scan: 128 wgs = 2 independent 64-wg groups.
// wg (j = blk>>1, bh = blk&1) owns units [8j,8j+8) x batches [64bh, 64bh+64).
// h exchanged via hfrag in MFMA-FRAGMENT-MAJOR layout:
//   hfrag[parity][bb=(bh*4+wv)*16+kt][lane][8 halves]
// consumer fragment (wv,kt) = ONE contiguous 1KB block (full line utilization);
// producer (j,bh) writes 4x256B contiguous chunks. All cross-wg traffic via
// LLC-direct (sc0 sc1) accesses, no fences. Distributed per-wg flags.
// This is the session's verified-best protocol (2490.9/2506 us). Three
// alternative sync designs (tagged-data HBM mailbox, XCD-pinned L2) measured
// >= this; the ~4us/step device-coherence round-trip is the structural floor.
// Only change vs round 0: scan bounded at tmax = max(group label_len)+1
// (group-uniform by construction; saves ~8 steps).
#define NWG 128
__global__ __launch_bounds__(256, 1) void lstm_kernel(
    const int* __restrict__ label_len,
    const float* __restrict__ h2h_w,   // [2560][512] fp32
    const float* __restrict__ h2h_b,   // [2560]
    const float* __restrict__ i2h_b,   // [2560]
    const signed char* __restrict__ pre8,    // [512][64][128][40] int8
    _Float16* __restrict__ hfrag,            // [2][8*16][64][8] fp16 (256 KB)
    float* __restrict__ xsel,                // [128][512] fp32
    int* __restrict__ flags) {               // 128 flags, 128B apart
  const int j   = blockIdx.x >> 1;
  const int bh  = blockIdx.x & 1;
  const int tid = threadIdx.x;
  const int lane = tid & 63;
  const int wv = tid >> 6;

  __shared__ _Float16 Wl[3 * 16 * 64 * 8];   // 48 KB, MFMA B-operand order
  __shared__ _Float16 s_s[64 * 48];          // 6 KB
  __shared__ int ll_s[64];

  for (int slot = tid; slot < 3 * 16 * 64; slot += 256) {
    int nt = slot / (16 * 64);
    int rem = slot - nt * (16 * 64);
    int kt = rem >> 6;
    int l = rem & 63;
    int p = nt * 16 + (l & 15);            // packed col: g*8+u (p<40), else zero pad
    int k0 = kt * 32 + (l >> 4) * 8;
    h16x8 tv;
    if (p < 40) {
      int r = (p >> 3) * 512 + j * 8 + (p & 7);
      const float* src = h2h_w + (size_t)r * 512 + k0;
#pragma unroll
      for (int q = 0; q < 8; q++) tv[q] = (_Float16)src[q];
    } else {
#pragma unroll
      for (int q = 0; q < 8; q++) tv[q] = (_Float16)0.f;
    }
    *(h16x8*)&Wl[slot * 8] = tv;
  }
  if (tid < 64) ll_s[tid] = label_len[bh * 64 + tid];

  // gate ownership: thread -> batch b'=tid>>2 (bp), units (ue, ue+1)
  const int ue = (tid & 3) * 2;
  const int bp = tid >> 2;             // 0..63
  float bias_r[2][5];
#pragma unroll
  for (int uu = 0; uu < 2; uu++)
#pragma unroll
    for (int g = 0; g < 5; g++)
      bias_r[uu][g] = h2h_b[g * 512 + j * 8 + ue + uu] + i2h_b[g * 512 + j * 8 + ue + uu];

  // producer store slot (fragment-major): block bb, lane_c, sub=ue
  const int pbb = (bh * 4 + (bp >> 4)) * 16 + (j >> 2);
  const int plc = (bp & 15) | ((j & 3) << 4);
  unsigned int* pdst0 = (unsigned int*)(hfrag + (size_t)pbb * 512 + plc * 8 + ue);
  unsigned int* pdst1 = (unsigned int*)(hfrag + 65536 + (size_t)pbb * 512 + plc * 8 + ue);

  float c_reg[2] = {0.f, 0.f};
  __syncthreads();

  int tmax = 0;
#pragma unroll 1
  for (int i = 0; i < 64; i++) tmax = max(tmax, ll_s[i]);
  tmax += 1;

#pragma unroll 1
  for (int t = 0; t < tmax; ++t) {
    // prefetch this wg's private pre[t] block (plain cached; overlaps poll)
    unsigned short pr[5];
    {
      const signed char* pt = pre8 + (((size_t)t * 64 + j) * 128 + bh * 64) * 40;
#pragma unroll
      for (int g = 0; g < 5; g++)
        pr[g] = *(const unsigned short*)&pt[bp * 40 + g * 8 + ue];
    }

    if (t > 0) {
      // wait for all 64 same-bh producers (lane-parallel distributed flags)
      if (wv == 0) {
        const int* fp = flags + (bh * 64 + lane) * 32;
        while (true) {
          int v = __hip_atomic_load(fp, __ATOMIC_RELAXED, __HIP_MEMORY_SCOPE_AGENT);
          if (__ballot(v >= t) == 0xFFFFFFFFFFFFFFFFull) break;
          __builtin_amdgcn_s_sleep(1);
        }
      }
      __syncthreads();

      // load 16 A-fragments: each is a contiguous 1KB block, lane*16B -- fully
      // coalesced LLC reads, issued back-to-back, single vmcnt(0)
      const _Float16* hpb = hfrag + ((t - 1) & 1) * 65536
                          + (size_t)((bh * 4 + wv) * 16) * 512 + lane * 8;
      u32x4 areg[16];
#pragma unroll
      for (int kt = 0; kt < 16; ++kt) {
        const void* ap = (const void*)(hpb + kt * 512);
        asm volatile("global_load_dwordx4 %0, %1, off sc0 sc1"
                     : "=v"(areg[kt]) : "v"(ap) : "memory");
      }
      asm volatile("s_waitcnt vmcnt(0)" ::: "memory");

      // GEMM: wave wv owns m-tile wv (16 rows); 3 n-tiles; K=512
      fx4 zero = {0.f, 0.f, 0.f, 0.f};
      fx4 acc[3] = {zero, zero, zero};
#pragma unroll
      for (int kt = 0; kt < 16; ++kt) {
        union { u32x4 u; h16x8 v; } a;
        a.u = areg[kt];
#pragma unroll
        for (int nt = 0; nt < 3; nt++) {
          h16x8 bfr = *(const h16x8*)&Wl[((nt * 16 + kt) * 64 + lane) * 8];
          acc[nt] = __builtin_amdgcn_mfma_f32_16x16x32_f16(a.v, bfr, acc[nt], 0, 0, 0);
        }
      }
#pragma unroll
      for (int nt = 0; nt < 3; nt++)
#pragma unroll
        for (int r = 0; r < 4; r++) {
          int b = wv * 16 + (lane >> 4) * 4 + r;
          s_s[b * 48 + nt * 16 + (lane & 15)] = (_Float16)acc[nt][r];
        }
      __syncthreads();
    }

    // gate phase
    float nh2[2];
#pragma unroll
    for (int uu = 0; uu < 2; uu++) {
      float sv[5];
#pragma unroll
      for (int g = 0; g < 5; g++) {
        signed char qb = (signed char)(uu == 0 ? (pr[g] & 0xFF) : (pr[g] >> 8));
        float base = (t > 0) ? (float)s_s[bp * 48 + g * 8 + ue + uu] : 0.f;
        sv[g] = base + (float)qb * PRE_INV + bias_r[uu][g];
      }
      float ing = 1.f / (1.f + __expf(-sv[0]));
      float fg  = 1.f / (1.f + __expf(-sv[1]));
      float og  = 1.f / (1.f + __expf(-sv[2]));
      float itv = fmaxf(sv[3], sv[4]);
      float nc = fg * c_reg[uu] + ing * itv;
      c_reg[uu] = nc;
      nh2[uu] = og * tanhf(nc);
    }
    {
      union { _Float16 h[2]; unsigned int u; } pk;
      pk.h[0] = (_Float16)nh2[0];
      pk.h[1] = (_Float16)nh2[1];
      __hip_atomic_store((t & 1) ? pdst1 : pdst0, pk.u,
                         __ATOMIC_RELAXED, __HIP_MEMORY_SCOPE_AGENT);
      if (ll_s[bp] == t) {
        union { float f[2]; ull u; } xk;
        xk.f[0] = nh2[0];
        xk.f[1] = nh2[1];
        __hip_atomic_store((ull*)&xsel[(bh * 64 + bp) * 512 + j * 8 + ue], xk.u,
                           __ATOMIC_RELAXED, __HIP_MEMORY_SCOPE_AGENT);
      }
    }

    // drain h stores to LLC, then arrive on our own flag line
    asm volatile("s_waitcnt vmcnt(0)" ::: "memory");
    __syncthreads();
    if (tid == 0)
      __hip_atomic_store(flags + (bh * 64 + j) * 32, t + 1,
                         __ATOMIC_RELAXED, __HIP_MEMORY_SCOPE_AGENT);
  }
}

// ---------------- small fp32 GEMM: Y[128,512] = X[128,512] @ W[512,512]^T + bias
__global__ __launch_bounds__(256) void fgemm_kernel(
    const float* __restrict__ X, const float* __restrict__ W,
    const float* __restrict__ bias, float* __restrict__ Y) {
  const int n0 = blockIdx.x * 64;
  const int m0 = blockIdx.y * 64;
  const int tid = threadIdx.x;
  const int tx = tid & 15, ty = tid >> 4;

  __shared__ float Xs[64 * 68];
  __shared__ float Wt[64 * 68];

  float acc[4][4] = {};
#pragma unroll 1
  for (int k0 = 0; k0 < 512; k0 += 64) {
#pragma unroll
    for (int q = 0; q < 4; q++) {
      int id = tid + q * 256;
      int r = id >> 4, c = id & 15;
      float4 xv = *(const float4*)&X[(m0 + r) * 512 + k0 + c * 4];
      *(float4*)&Xs[r * 68 + c * 4] = xv;
      float4 wvv = *(const float4*)&W[(n0 + r) * 512 + k0 + c * 4];
      Wt[(c * 4 + 0) * 68 + r] = wvv.x;
      Wt[(c * 4 + 1) * 68 + r] = wvv.y;
      Wt[(c * 4 + 2) * 68 + r] = wvv.z;
      Wt[(c * 4 + 3) * 68 + r] = wvv.w;
    }
    __syncthreads();
#pragma unroll 4
    for (int kk = 0; kk < 64; kk++) {
      float a[4], b[4];
#pragma unroll
      for (int i = 0; i < 4; i++) a[i] = Xs[(ty * 4 + i) * 68 + kk];
#pragma unroll
      for (int jj = 0; jj < 4; jj++) b[jj] = Wt[kk * 68 + tx * 4 + jj];
#pragma unroll
      for (int i = 0; i < 4; i++)
#pragma unroll
        for (int jj = 0; jj < 4; jj++) acc[i][jj] += a[i] * b[jj];
    }
    __syncthreads();
  }
#pragma unroll
  for (int i = 0; i < 4; i++)
#pragma unroll
    for (int jj = 0; jj < 4; jj++) {
      int n = n0 + tx * 4 + jj;
      Y[(m0 + ty * 4 + i) * 512 + n] = acc[i][jj] + bias[n];
    }
}

// ---------------- batchnorm over batch dim (in-place), optional relu
__global__ __launch_bounds__(256) void bn_kernel(float* __restrict__ Y,
    const float* __restrict__ gam, const float* __restrict__ bet, int relu) {
  const int cx = threadIdx.x & 15;
  const int rg = threadIdx.x >> 4;
  const int col = blockIdx.x * 16 + cx;
  __shared__ float rs[16 * 17], rs2[16 * 17];
  float s = 0.f, s2 = 0.f;
#pragma unroll
  for (int i = 0; i < 8; i++) {
    float v = Y[(rg * 8 + i) * 512 + col];
    s += v; s2 += v * v;
  }
  rs[rg * 17 + cx] = s;
  rs2[rg * 17 + cx] = s2;
  __syncthreads();
  if (threadIdx.x < 16) {
    float S = 0.f, S2 = 0.f;
#pragma unroll
    for (int q = 0; q < 16; q++) { S += rs[q * 17 + threadIdx.x]; S2 += rs2[q * 17 + threadIdx.x]; }
    float mean = S / 128.f;
    float var = S2 / 128.f - mean * mean;
    rs[threadIdx.x] = mean;
    rs2[threadIdx.x] = rsqrtf(var + 1e-5f);
  }
  __syncthreads();
  float mean = rs[cx], rstd = rs2[cx];
  float gv = gam[col], bv = bet[col];
#pragma unroll
  for (int i = 0; i < 8; i++) {
    int idx = (rg * 8 + i) * 512 + col;
    float v = (Y[idx] - mean) * rstd * gv + bv;
    if (relu) v = fmaxf(v, 0.f);
    Y[idx] = v;
  }
}

extern "C" void kernel_launch(void* const* d_in, const int* in_sizes, int n_in,
                              void* d_out, int out_size, void* d_ws, size_t ws_size,
                              hipStream_t stream) {
  const int* label      = (const int*)d_in[0];
  const int* label_len  = (const int*)d_in[1];
  const float* embed_w  = (const float*)d_in[2];
  const float* i2h_w    = (const float*)d_in[3];
  const float* i2h_b    = (const float*)d_in[4];
  const float* h2h_w    = (const float*)d_in[5];
  const float* h2h_b    = (const float*)d_in[6];
  const float* lin0_w   = (const float*)d_in[7];
  const float* lin0_b   = (const float*)d_in[8];
  const float* bn0_g    = (const float*)d_in[9];
  const float* bn0_b    = (const float*)d_in[10];
  const float* lin1_w   = (const float*)d_in[11];
  const float* lin1_b   = (const float*)d_in[12];
  const float* bn1_g    = (const float*)d_in[13];
  const float* bn1_b    = (const float*)d_in[14];
  float* out = (float*)d_out;
  char* ws = (char*)d_ws;

  const size_t OFF_FLAGS = 0;                                      // 16 KB
  const size_t OFF_I2H  = 16384;
  const size_t OFF_PRE  = OFF_I2H + (size_t)2560 * 512 * 2;        // fp16 i2h
  const size_t OFF_H    = OFF_PRE + (size_t)512 * 128 * 2560;      // int8 pre
  const size_t OFF_XSEL = OFF_H + (size_t)2 * 128 * 512 * 2;       // fp16 hfrag
  const size_t OFF_Y0   = OFF_XSEL + (size_t)128 * 512 * 4;

  int* flags = (int*)(ws + OFF_FLAGS);
  _Float16* i2h_h = (_Float16*)(ws + OFF_I2H);
  signed char* pre8 = (signed char*)(ws + OFF_PRE);
  _Float16* hfrag = (_Float16*)(ws + OFF_H);
  float* xsel = (float*)(ws + OFF_XSEL);
  float* y0   = (float*)(ws + OFF_Y0);

  hipMemsetAsync(ws + OFF_FLAGS, 0, 16384, stream);

  {
    int n4 = (2560 * 512) / 4;
    f2h_kernel<<<(n4 + 255) / 256, 256, 0, stream>>>(i2h_w, i2h_h, n4);
  }
  gemm1_kernel<<<dim3(20, 512), 256, 0, stream>>>(label, label_len, embed_w, i2h_h, pre8);
  lstm_kernel<<<dim3(NWG), 256, 0, stream>>>(label_len, h2h_w, h2h_b, i2h_b, pre8, hfrag, xsel, flags);
  fgemm_kernel<<<dim3(8, 2), 256, 0, stream>>>(xsel, lin0_w, lin0_b, y0);
  bn_kernel<<<dim3(32), 256, 0, stream>>>(y0, bn0_g, bn0_b, 1);
  fgemm_kernel<<<dim3(8, 2), 256, 0, stream>>>(y0, lin1_w, lin1_b, out);
  bn_kernel<<<dim3(32), 256, 0, stream>>>(out, bn1_g, bn1_b, 0);
}